// Round 4
// baseline (166.265 us; speedup 1.0000x reference)
//
#include <hip/hip_runtime.h>

#define NSLOTS 131072
#define NMASK  (NSLOTS-1)
#define NBATCH 256
#define DMEM   64
#define DIN    256
#define DCOMB  71
#define SPB    64                 // slots per stats tile
#define NBLK   (NSLOTS/SPB)       // 2048
#define SPBF   256                // slots per final block
#define BPBF   64                 // batches per final block
#define EPSF   1e-8f

typedef unsigned int   u32;
typedef unsigned short u16;
typedef __bf16 bf16x8 __attribute__((ext_vector_type(8)));
typedef float  f32x4  __attribute__((ext_vector_type(4)));

__device__ __forceinline__ u16 f2bf(float f) {
  u32 u = __builtin_bit_cast(u32, f);
  u += 0x7fffu + ((u >> 16) & 1u);          // RNE
  return (u16)(u >> 16);
}
__device__ __forceinline__ float bf2f(u16 v) {
  return __builtin_bit_cast(float, ((u32)v) << 16);
}
__device__ __forceinline__ u32 pk2(float a, float b) {
  return (u32)f2bf(a) | ((u32)f2bf(b) << 16);
}
__device__ __forceinline__ float blo(u32 u){ return __builtin_bit_cast(float, u << 16); }
__device__ __forceinline__ float bhi(u32 u){ return __builtin_bit_cast(float, u & 0xffff0000u); }

// ---------------- kernel 1: combined GEMM + per-batch params ----------------
// params[b*8]: {abk = ks/kn, C = |ks|, gate, ck0, ck1, ck2, -, -}
__global__ __launch_bounds__(128) void ntm_prep(
    const float* __restrict__ inp, const float* __restrict__ W,
    const float* __restrict__ bias, u16* __restrict__ keysbf,
    float* __restrict__ params)
{
  __shared__ float comb[DCOMB];
  const int b = blockIdx.x;
  const int t = threadIdx.x;
  if (t < DCOMB) {
    float acc = bias[t];
    const float* ip = inp + (size_t)b * DIN;
    for (int i = 0; i < DIN; ++i) acc = fmaf(ip[i], W[i*DCOMB + t], acc);
    comb[t] = acc;
  }
  __syncthreads();
  if (t < 64) {
    float k = comb[t];
    keysbf[b*64 + t] = f2bf(k);
    float sq = k * k;
#pragma unroll
    for (int d = 1; d < 64; d <<= 1) sq += __shfl_xor(sq, d, 64);
    if (t == 0) {
      float kn = sqrtf(sq);
      float ks = comb[64];
      params[b*8+0] = ks / kn;                         // abk
      params[b*8+1] = fabsf(ks);                       // softmax shift C (>= max logit)
      params[b*8+2] = 1.f/(1.f + __expf(-comb[65]));   // gate
      float c0 = comb[66], c1 = comb[67], c2 = comb[68];
      float mx = fmaxf(c0, fmaxf(c1, c2));
      float e0 = __expf(c0-mx), e1 = __expf(c1-mx), e2 = __expf(c2-mx);
      float inv = 1.f/(e0+e1+e2);
      params[b*8+3] = e0*inv; params[b*8+4] = e1*inv; params[b*8+5] = e2*inv;
    }
  }
}

// ---------------- kernel 2: per-(tile,half) sum of exp(l - C) ----------------
__global__ __launch_bounds__(512, 8) void ntm_stats(
    const u16* __restrict__ keysbf, const float* __restrict__ memory,
    const float* __restrict__ params, float* __restrict__ sumpart)
{
  __shared__ __align__(16) u16 meml[SPB*DMEM];      // 8 KB, swizzled
  __shared__ float invmn[SPB];
  const int t     = threadIdx.x;
  const int s0    = blockIdx.x * SPB;
  const int bbase = blockIdx.y * 128;

  { // memory tile -> bf16 LDS + 1/norm
    int r = t >> 3, c8 = t & 7;
    const float* mp = memory + (size_t)(s0 + r) * DMEM + c8 * 8;
    float4 f0 = *(const float4*)mp;
    float4 f1 = *(const float4*)(mp + 4);
    uint4 v;
    v.x = pk2(f0.x, f0.y); v.y = pk2(f0.z, f0.w);
    v.z = pk2(f1.x, f1.y); v.w = pk2(f1.z, f1.w);
    *(uint4*)&meml[r*DMEM + ((c8 ^ (r & 7)) << 3)] = v;
    float sq = f0.x*f0.x + f0.y*f0.y + f0.z*f0.z + f0.w*f0.w
             + f1.x*f1.x + f1.y*f1.y + f1.z*f1.z + f1.w*f1.w;
    sq += __shfl_xor(sq, 1, 64);
    sq += __shfl_xor(sq, 2, 64);
    sq += __shfl_xor(sq, 4, 64);
    if (c8 == 0) invmn[r] = rsqrtf(sq);
  }
  __syncthreads();

  const int w = t >> 6, L = t & 63;
  const int li = L & 15, hi4 = L >> 4;
  const int bb = bbase + w*16 + li;
  const uint4* kb = (const uint4*)(keysbf + (size_t)bb * DMEM);
  f32x4 zero = {0.f, 0.f, 0.f, 0.f};
  f32x4 acc[4];
#pragma unroll
  for (int rt = 0; rt < 4; ++rt) acc[rt] = zero;

#pragma unroll
  for (int ks = 0; ks < 2; ++ks) {
    int cb = ks*4 + hi4;
    bf16x8 bfr = __builtin_bit_cast(bf16x8, kb[cb]);
#pragma unroll
    for (int rt = 0; rt < 4; ++rt) {
      int r = rt*16 + li;
      bf16x8 af = __builtin_bit_cast(bf16x8, *(const uint4*)&meml[r*DMEM + ((cb ^ (r&7)) << 3)]);
      acc[rt] = __builtin_amdgcn_mfma_f32_16x16x32_bf16(af, bfr, acc[rt], 0, 0, 0);
    }
  }

  float abk = params[bb*8 + 0];
  float C   = params[bb*8 + 1];
  float s = 0.f;
#pragma unroll
  for (int rt = 0; rt < 4; ++rt)
#pragma unroll
    for (int r = 0; r < 4; ++r) {
      int sl = rt*16 + hi4*4 + r;
      s += __expf(acc[rt][r] * abk * invmn[sl] - C);
    }
  s += __shfl_xor(s, 16, 64);
  s += __shfl_xor(s, 32, 64);
  if (hi4 == 0) sumpart[(size_t)bb*NBLK + blockIdx.x] = s;
}

// ---------------- kernel 3: global S per batch ----------------
__global__ __launch_bounds__(256) void ntm_reduce(
    const float* __restrict__ sumpart, float* __restrict__ Sv)
{
  __shared__ float red[4];
  const int b = blockIdx.x, t = threadIdx.x;
  const int w = t >> 6, L = t & 63;
  float s = 0.f;
  for (int i = t; i < NBLK; i += 256) s += sumpart[(size_t)b*NBLK + i];
#pragma unroll
  for (int d = 1; d < 64; d <<= 1) s += __shfl_xor(s, d, 64);
  if (L == 0) red[w] = s;
  __syncthreads();
  if (t == 0) Sv[b] = red[0] + red[1] + red[2] + red[3];
}

// ---------------- kernel 4: 256-slot x 64-batch tiles; long contiguous conv ----------------
__global__ __launch_bounds__(512, 6) void ntm_final(
    const u16* __restrict__ keysbf, const float* __restrict__ memory,
    const float* __restrict__ params, const float* __restrict__ Sv,
    const float* __restrict__ prev, float* __restrict__ out)
{
  __shared__ __align__(16) u16 pool[BPBF*SPBF];     // 32 KB: wg' bf16, swizzled 8B chunks
  __shared__ __align__(16) u16 meml[64*DMEM];       // 8 KB subtile, swizzled
  __shared__ __align__(16) u16 halom[2*DMEM];
  __shared__ float invmn[64];
  __shared__ float invhn[2];
  __shared__ u16 hlo[BPBF], hhi[BPBF];
  const int t     = threadIdx.x;
  const int s0    = blockIdx.x * SPBF;
  const int bbase = blockIdx.y * BPBF;

  if (t < 128) { // halo memory rows (slots s0-1, s0+256 circular)
    int h = t >> 6, m = t & 63;
    int gs = (s0 + (h ? SPBF : -1)) & NMASK;
    float v = memory[(size_t)gs * DMEM + m];
    halom[h*DMEM + m] = f2bf(v);
    float sq = v * v;
#pragma unroll
    for (int d = 1; d < 64; d <<= 1) sq += __shfl_xor(sq, d, 64);
    if (m == 0) invhn[h] = rsqrtf(sq);
  }

  const int w   = t >> 6, L = t & 63;
  const int li  = L & 15, hi4 = L >> 4;
  const int bt  = w & 3;           // batch tile (16 batches)
  const int sh  = w >> 2;          // slot half of subtile (32 slots)
  const int bb  = bbase + bt*16 + li;
  const int prow = bt*16 + li;     // pool row 0..63
  const uint4* kb = (const uint4*)(keysbf + (size_t)bb * DMEM);
  const float abk  = params[bb*8+0];
  const float C    = params[bb*8+1];
  const float wfac = params[bb*8+2] / Sv[bb];

  for (int st = 0; st < 4; ++st) {
    { // stage memory subtile (64 slots)
      int r = t >> 3, c8 = t & 7;
      const float* mp = memory + (size_t)(s0 + st*64 + r) * DMEM + c8 * 8;
      float4 f0 = *(const float4*)mp;
      float4 f1 = *(const float4*)(mp + 4);
      uint4 v;
      v.x = pk2(f0.x, f0.y); v.y = pk2(f0.z, f0.w);
      v.z = pk2(f1.x, f1.y); v.w = pk2(f1.z, f1.w);
      *(uint4*)&meml[r*DMEM + ((c8 ^ (r & 7)) << 3)] = v;
      float sq = f0.x*f0.x + f0.y*f0.y + f0.z*f0.z + f0.w*f0.w
               + f1.x*f1.x + f1.y*f1.y + f1.z*f1.z + f1.w*f1.w;
      sq += __shfl_xor(sq, 1, 64);
      sq += __shfl_xor(sq, 2, 64);
      sq += __shfl_xor(sq, 4, 64);
      if (c8 == 0) invmn[r] = rsqrtf(sq);
    }
    __syncthreads();

    f32x4 zero = {0.f, 0.f, 0.f, 0.f};
    f32x4 acc[2] = {zero, zero};
#pragma unroll
    for (int ks = 0; ks < 2; ++ks) {
      int cb = ks*4 + hi4;
      bf16x8 bfr = __builtin_bit_cast(bf16x8, kb[cb]);
#pragma unroll
      for (int rt = 0; rt < 2; ++rt) {
        int r = sh*32 + rt*16 + li;
        bf16x8 af = __builtin_bit_cast(bf16x8, *(const uint4*)&meml[r*DMEM + ((cb ^ (r&7)) << 3)]);
        acc[rt] = __builtin_amdgcn_mfma_f32_16x16x32_bf16(af, bfr, acc[rt], 0, 0, 0);
      }
    }

    // wg' -> pool (swizzled 8B chunks within this subtile's 16-chunk group)
#pragma unroll
    for (int rt = 0; rt < 2; ++rt) {
      int sbase = sh*32 + rt*16 + hi4*4;   // slot within subtile
      float wv[4];
#pragma unroll
      for (int r = 0; r < 4; ++r)
        wv[r] = __expf(acc[rt][r] * abk * invmn[sbase + r] - C) * wfac;
      uint2 pkd;
      pkd.x = pk2(wv[0], wv[1]);
      pkd.y = pk2(wv[2], wv[3]);
      int chunk = st*16 + ((sbase >> 2) ^ (prow & 15));
      *(uint2*)&pool[prow*SPBF + chunk*4] = pkd;
    }
    __syncthreads();
  }

  // halo wg' (VALU dot, keys from L2)
  if (t < 128) {
    int hb = t & 63, hh = t >> 6;
    int gb = bbase + hb;
    const uint4* kb2 = (const uint4*)(keysbf + (size_t)gb * DMEM);
    float dot = 0.f;
#pragma unroll
    for (int mb = 0; mb < 8; ++mb) {
      uint4 kv = kb2[mb];
      uint4 mv = *(const uint4*)&halom[hh*DMEM + mb*8];
      dot += blo(kv.x)*blo(mv.x) + bhi(kv.x)*bhi(mv.x);
      dot += blo(kv.y)*blo(mv.y) + bhi(kv.y)*bhi(mv.y);
      dot += blo(kv.z)*blo(mv.z) + bhi(kv.z)*bhi(mv.z);
      dot += blo(kv.w)*blo(mv.w) + bhi(kv.w)*bhi(mv.w);
    }
    float abk2 = params[gb*8+0], C2 = params[gb*8+1], gg2 = params[gb*8+2];
    float l = dot * abk2 * invhn[hh];
    u16 hv = f2bf(__expf(l - C2) * gg2 / Sv[gb]);
    if (hh) hhi[hb] = hv; else hlo[hb] = hv;
  }
  __syncthreads();

  // conv + output: 8 threads per row, 32 contiguous slots per thread (1 KB runs per row)
  {
    const int row = t >> 3;          // 0..63
    const int seg = t & 7;           // 0..7
    const int bb2 = bbase + row;
    const float gg = params[bb2*8+2];
    const float c0 = params[bb2*8+3], c1 = params[bb2*8+4], c2 = params[bb2*8+5];
    const float og = 1.f - gg;
    const float* pv = prev + (size_t)bb2 * NSLOTS;
    const float4* pseg = (const float4*)(pv + s0 + seg*32);
    float4 pr[8];
#pragma unroll
    for (int j = 0; j < 8; ++j) pr[j] = pseg[j];
    uint2 wu[8];
#pragma unroll
    for (int j = 0; j < 8; ++j) {
      int chunk = seg*8 + j;
      int cs = (chunk & 48) | ((chunk ^ row) & 15);
      wu[j] = *(const uint2*)&pool[row*SPBF + cs*4];
    }
    float lpr = __shfl_up(pr[7].w, 1, 64);
    float rpr = __shfl_down(pr[0].x, 1, 64);
    float lw  = __shfl_up(bhi(wu[7].y), 1, 64);
    float rw  = __shfl_down(blo(wu[0].x), 1, 64);
    if (seg == 0) { lpr = pv[(s0 - 1) & NMASK];    lw = bf2f(hlo[row]); }
    if (seg == 7) { rpr = pv[(s0 + SPBF) & NMASK]; rw = bf2f(hhi[row]); }

    float4* oseg = (float4*)(out + (size_t)bb2 * NSLOTS + s0 + seg*32);
    float lp = lpr, lwv = lw;        // value at slot (seg*32 - 1)
#pragma unroll
    for (int j = 0; j < 8; ++j) {
      float w0 = blo(wu[j].x), w1 = bhi(wu[j].x), w2 = blo(wu[j].y), w3 = bhi(wu[j].y);
      float np, nw;
      if (j < 7) { np = pr[j+1].x; nw = blo(wu[j+1].x); }
      else       { np = rpr;       nw = rw; }
      float fm1 = fmaf(og, lp,       lwv);
      float f0  = fmaf(og, pr[j].x,  w0);
      float f1  = fmaf(og, pr[j].y,  w1);
      float f2  = fmaf(og, pr[j].z,  w2);
      float f3  = fmaf(og, pr[j].w,  w3);
      float f4  = fmaf(og, np,       nw);
      float4 o;
      o.x = c0*fm1 + c1*f0 + c2*f1;
      o.y = c0*f0  + c1*f1 + c2*f2;
      o.z = c0*f1  + c1*f2 + c2*f3;
      o.w = c0*f2  + c1*f3 + c2*f4;
      oseg[j] = o;
      lp = pr[j].w; lwv = w3;
    }
  }
}

extern "C" void kernel_launch(void* const* d_in, const int* in_sizes, int n_in,
                              void* d_out, int out_size, void* d_ws, size_t ws_size,
                              hipStream_t stream)
{
  (void)in_sizes; (void)n_in; (void)out_size;
  const float* inp    = (const float*)d_in[0];
  const float* memory = (const float*)d_in[1];
  const float* prev   = (const float*)d_in[2];
  const float* W      = (const float*)d_in[3];
  const float* bias   = (const float*)d_in[4];
  float* out = (float*)d_out;
  char*  ws  = (char*)d_ws;

  u16*   keysbf = (u16*)ws;                    // 32 KB
  float* params = (float*)(ws + 32768);        // 8 KB
  float* Sv     = (float*)(ws + 40960);        // 1 KB
  float* sumpart;
  const size_t partbytes = (size_t)NBATCH * NBLK * 4u;
  if (ws_size >= 49152 + partbytes) {
    sumpart = (float*)(ws + 49152);
  } else {
    // scratch inside d_out (fully overwritten by ntm_final afterwards)
    sumpart = out;
  }

  hipLaunchKernelGGL(ntm_prep,   dim3(NBATCH),        dim3(128), 0, stream, inp, W, bias, keysbf, params);
  hipLaunchKernelGGL(ntm_stats,  dim3(NBLK, 2),       dim3(512), 0, stream, keysbf, memory, params, sumpart);
  hipLaunchKernelGGL(ntm_reduce, dim3(NBATCH),        dim3(256), 0, stream, sumpart, Sv);
  hipLaunchKernelGGL(ntm_final,  dim3(NSLOTS/SPBF, NBATCH/BPBF), dim3(512), 0, stream, keysbf, memory, params, Sv, prev, out);
}

// Round 5
// 164.167 us; speedup vs baseline: 1.0128x; 1.0128x over previous
//
#include <hip/hip_runtime.h>

#define NSLOTS 131072
#define NMASK  (NSLOTS-1)
#define NBATCH 256
#define DMEM   64
#define DIN    256
#define DCOMB  71
#define SPB    64                 // slots per fallback-stats tile
#define NBLK   (NSLOTS/SPB)       // 2048
#define EPSF   1e-8f

typedef unsigned int   u32;
typedef unsigned short u16;
typedef __bf16 bf16x8 __attribute__((ext_vector_type(8)));
typedef float  f32x4  __attribute__((ext_vector_type(4)));

__device__ __forceinline__ u16 f2bf(float f) {
  u32 u = __builtin_bit_cast(u32, f);
  u += 0x7fffu + ((u >> 16) & 1u);          // RNE
  return (u16)(u >> 16);
}
__device__ __forceinline__ float bf2f(u16 v) {
  return __builtin_bit_cast(float, ((u32)v) << 16);
}
__device__ __forceinline__ u32 pk2(float a, float b) {
  return (u32)f2bf(a) | ((u32)f2bf(b) << 16);
}
__device__ __forceinline__ float blo(u32 u){ return __builtin_bit_cast(float, u << 16); }
__device__ __forceinline__ float bhi(u32 u){ return __builtin_bit_cast(float, u & 0xffff0000u); }

// ---------------- kernel 1: combined GEMM + per-batch params ----------------
// params[b*8]: {abk = ks/kn, C = |ks|, gate, ck0, ck1, ck2, -, -}
__global__ __launch_bounds__(128) void ntm_prep(
    const float* __restrict__ inp, const float* __restrict__ W,
    const float* __restrict__ bias, u16* __restrict__ keysbf,
    float* __restrict__ params)
{
  __shared__ float comb[DCOMB];
  const int b = blockIdx.x;
  const int t = threadIdx.x;
  if (t < DCOMB) {
    float acc = bias[t];
    const float* ip = inp + (size_t)b * DIN;
    for (int i = 0; i < DIN; ++i) acc = fmaf(ip[i], W[i*DCOMB + t], acc);
    comb[t] = acc;
  }
  __syncthreads();
  if (t < 64) {
    float k = comb[t];
    keysbf[b*64 + t] = f2bf(k);
    float sq = k * k;
#pragma unroll
    for (int d = 1; d < 64; d <<= 1) sq += __shfl_xor(sq, d, 64);
    if (t == 0) {
      float kn = sqrtf(sq);
      float ks = comb[64];
      params[b*8+0] = ks / kn;                         // abk
      params[b*8+1] = fabsf(ks);                       // softmax shift C (>= max logit)
      params[b*8+2] = 1.f/(1.f + __expf(-comb[65]));   // gate
      float c0 = comb[66], c1 = comb[67], c2 = comb[68];
      float mx = fmaxf(c0, fmaxf(c1, c2));
      float e0 = __expf(c0-mx), e1 = __expf(c1-mx), e2 = __expf(c2-mx);
      float inv = 1.f/(e0+e1+e2);
      params[b*8+3] = e0*inv; params[b*8+4] = e1*inv; params[b*8+5] = e2*inv;
    }
  }
}

// ---------------- kernel A: dots -> u = exp(l - C) (bf16, coalesced) + partial sums ----------------
// tile: 256 slots x 64 batches. grid (512, 4).
__global__ __launch_bounds__(512, 6) void ntm_dots(
    const u16* __restrict__ keysbf, const float* __restrict__ memory,
    const float* __restrict__ params, u16* __restrict__ ug,
    float* __restrict__ sumpart)
{
  __shared__ __align__(16) u16 pool[64*256];        // 32 KB: u bf16, swizzled 8B chunks
  __shared__ __align__(16) u16 meml[64*DMEM];       // 8 KB subtile, swizzled
  __shared__ float invmn[64];
  const int t     = threadIdx.x;
  const int s0    = blockIdx.x * 256;
  const int bbase = blockIdx.y * 64;

  const int w   = t >> 6, L = t & 63;
  const int li  = L & 15, hi4 = L >> 4;
  const int bt  = w & 3;            // batch tile (16 batches)
  const int sh  = w >> 2;           // slot half of subtile (32 slots)
  const int bb  = bbase + bt*16 + li;
  const int prow = bt*16 + li;      // pool row 0..63
  const uint4* kb = (const uint4*)(keysbf + (size_t)bb * DMEM);
  const float abk = params[bb*8+0];
  const float C   = params[bb*8+1];
  float s_acc = 0.f;

  for (int st = 0; st < 4; ++st) {
    { // stage memory subtile (64 slots)
      int r = t >> 3, c8 = t & 7;
      const float* mp = memory + (size_t)(s0 + st*64 + r) * DMEM + c8 * 8;
      float4 f0 = *(const float4*)mp;
      float4 f1 = *(const float4*)(mp + 4);
      uint4 v;
      v.x = pk2(f0.x, f0.y); v.y = pk2(f0.z, f0.w);
      v.z = pk2(f1.x, f1.y); v.w = pk2(f1.z, f1.w);
      *(uint4*)&meml[r*DMEM + ((c8 ^ (r & 7)) << 3)] = v;
      float sq = f0.x*f0.x + f0.y*f0.y + f0.z*f0.z + f0.w*f0.w
               + f1.x*f1.x + f1.y*f1.y + f1.z*f1.z + f1.w*f1.w;
      sq += __shfl_xor(sq, 1, 64);
      sq += __shfl_xor(sq, 2, 64);
      sq += __shfl_xor(sq, 4, 64);
      if (c8 == 0) invmn[r] = rsqrtf(sq);
    }
    __syncthreads();

    f32x4 zero = {0.f, 0.f, 0.f, 0.f};
    f32x4 acc[2] = {zero, zero};
#pragma unroll
    for (int ks = 0; ks < 2; ++ks) {
      int cb = ks*4 + hi4;
      bf16x8 bfr = __builtin_bit_cast(bf16x8, kb[cb]);
#pragma unroll
      for (int rt = 0; rt < 2; ++rt) {
        int r = sh*32 + rt*16 + li;
        bf16x8 af = __builtin_bit_cast(bf16x8, *(const uint4*)&meml[r*DMEM + ((cb ^ (r&7)) << 3)]);
        acc[rt] = __builtin_amdgcn_mfma_f32_16x16x32_bf16(af, bfr, acc[rt], 0, 0, 0);
      }
    }

    // u -> pool (swizzled 8B chunks within this subtile's 16-chunk group)
#pragma unroll
    for (int rt = 0; rt < 2; ++rt) {
      int sbase = sh*32 + rt*16 + hi4*4;   // slot within subtile
      float wv[4];
#pragma unroll
      for (int r = 0; r < 4; ++r)
        wv[r] = __expf(acc[rt][r] * abk * invmn[sbase + r] - C);
      s_acc += wv[0] + wv[1] + wv[2] + wv[3];
      uint2 pkd;
      pkd.x = pk2(wv[0], wv[1]);
      pkd.y = pk2(wv[2], wv[3]);
      int chunk = st*16 + ((sbase >> 2) ^ (prow & 15));
      *(uint2*)&pool[prow*256 + chunk*4] = pkd;
    }
    __syncthreads();
  }

  // partial sums: reduce over hi4 groups (this wave covers 128 slots for batch bb)
  s_acc += __shfl_xor(s_acc, 16, 64);
  s_acc += __shfl_xor(s_acc, 32, 64);
  if (hi4 == 0) sumpart[(size_t)bb*1024 + blockIdx.x*2 + sh] = s_acc;

  // write u coalesced: 8 threads/row, 64 B each (512 B contiguous per row)
  {
    int row = t >> 3, seg = t & 7;
    uint2 wu[8];
#pragma unroll
    for (int j = 0; j < 8; ++j) {
      int c = seg*8 + j;
      int cs = (c & 48) | ((c ^ row) & 15);
      wu[j] = *(const uint2*)&pool[row*256 + cs*4];
    }
    uint4* dst = (uint4*)(ug + (size_t)(bbase + row) * NSLOTS + s0 + seg*32);
#pragma unroll
    for (int j2 = 0; j2 < 4; ++j2) {
      uint4 v; v.x = wu[j2*2].x; v.y = wu[j2*2].y; v.z = wu[j2*2+1].x; v.w = wu[j2*2+1].y;
      dst[j2] = v;
    }
  }
}

// ---------------- kernel 3: global S per batch ----------------
__global__ __launch_bounds__(256) void ntm_reduce(
    const float* __restrict__ sumpart, float* __restrict__ Sv, int nparts)
{
  __shared__ float red[4];
  const int b = blockIdx.x, t = threadIdx.x;
  const int w = t >> 6, L = t & 63;
  float s = 0.f;
  for (int i = t; i < nparts; i += 256) s += sumpart[(size_t)b*nparts + i];
#pragma unroll
  for (int d = 1; d < 64; d <<= 1) s += __shfl_xor(s, d, 64);
  if (L == 0) red[w] = s;
  __syncthreads();
  if (t == 0) Sv[b] = red[0] + red[1] + red[2] + red[3];
}

// ---------------- kernel B: pure streaming gate-blend + 3-tap circular conv ----------------
// grid (16, 256), 256 threads; block covers one batch row x 8192 slots.
__global__ __launch_bounds__(256, 8) void ntm_conv(
    const u16* __restrict__ ug, const float* __restrict__ params,
    const float* __restrict__ Sv, const float* __restrict__ prev,
    float* __restrict__ out)
{
  const int b  = blockIdx.y;
  const int c0 = blockIdx.x * 8192;
  const int t  = threadIdx.x;
  const float gg  = params[b*8+2];
  const float c0f = params[b*8+3], c1f = params[b*8+4], c2f = params[b*8+5];
  const float og  = 1.f - gg;
  const float gs  = gg / Sv[b];
  const float* pv = prev + (size_t)b * NSLOTS;
  const u16*   uv = ug   + (size_t)b * NSLOTS;
  float*       ov = out  + (size_t)b * NSLOTS;
#pragma unroll 4
  for (int i = 0; i < 32; ++i) {
    int s  = c0 + i*256 + t;
    int sm = (s - 1) & NMASK;
    int sp = (s + 1) & NMASK;
    float fm = fmaf(og, pv[sm], gs * bf2f(uv[sm]));
    float f0 = fmaf(og, pv[s],  gs * bf2f(uv[s]));
    float fp = fmaf(og, pv[sp], gs * bf2f(uv[sp]));
    ov[s] = c0f*fm + c1f*f0 + c2f*fp;
  }
}

// ================= fallback path (ws too small): round-3 validated kernels =================
__global__ __launch_bounds__(512, 8) void ntm_stats_fb(
    const u16* __restrict__ keysbf, const float* __restrict__ memory,
    const float* __restrict__ params, float* __restrict__ sumpart)
{
  __shared__ __align__(16) u16 meml[SPB*DMEM];
  __shared__ float invmn[SPB];
  const int t     = threadIdx.x;
  const int s0    = blockIdx.x * SPB;
  const int bbase = blockIdx.y * 128;
  {
    int r = t >> 3, c8 = t & 7;
    const float* mp = memory + (size_t)(s0 + r) * DMEM + c8 * 8;
    float4 f0 = *(const float4*)mp;
    float4 f1 = *(const float4*)(mp + 4);
    uint4 v;
    v.x = pk2(f0.x, f0.y); v.y = pk2(f0.z, f0.w);
    v.z = pk2(f1.x, f1.y); v.w = pk2(f1.z, f1.w);
    *(uint4*)&meml[r*DMEM + ((c8 ^ (r & 7)) << 3)] = v;
    float sq = f0.x*f0.x + f0.y*f0.y + f0.z*f0.z + f0.w*f0.w
             + f1.x*f1.x + f1.y*f1.y + f1.z*f1.z + f1.w*f1.w;
    sq += __shfl_xor(sq, 1, 64);
    sq += __shfl_xor(sq, 2, 64);
    sq += __shfl_xor(sq, 4, 64);
    if (c8 == 0) invmn[r] = rsqrtf(sq);
  }
  __syncthreads();
  const int w = t >> 6, L = t & 63;
  const int li = L & 15, hi4 = L >> 4;
  const int bb = bbase + w*16 + li;
  const uint4* kb = (const uint4*)(keysbf + (size_t)bb * DMEM);
  f32x4 zero = {0.f, 0.f, 0.f, 0.f};
  f32x4 acc[4];
#pragma unroll
  for (int rt = 0; rt < 4; ++rt) acc[rt] = zero;
#pragma unroll
  for (int ks = 0; ks < 2; ++ks) {
    int cb = ks*4 + hi4;
    bf16x8 bfr = __builtin_bit_cast(bf16x8, kb[cb]);
#pragma unroll
    for (int rt = 0; rt < 4; ++rt) {
      int r = rt*16 + li;
      bf16x8 af = __builtin_bit_cast(bf16x8, *(const uint4*)&meml[r*DMEM + ((cb ^ (r&7)) << 3)]);
      acc[rt] = __builtin_amdgcn_mfma_f32_16x16x32_bf16(af, bfr, acc[rt], 0, 0, 0);
    }
  }
  float abk = params[bb*8 + 0];
  float C   = params[bb*8 + 1];
  float s = 0.f;
#pragma unroll
  for (int rt = 0; rt < 4; ++rt)
#pragma unroll
    for (int r = 0; r < 4; ++r) {
      int sl = rt*16 + hi4*4 + r;
      s += __expf(acc[rt][r] * abk * invmn[sl] - C);
    }
  s += __shfl_xor(s, 16, 64);
  s += __shfl_xor(s, 32, 64);
  if (hi4 == 0) sumpart[(size_t)bb*NBLK + blockIdx.x] = s;
}

__global__ __launch_bounds__(512, 8) void ntm_final_fb(
    const u16* __restrict__ keysbf, const float* __restrict__ memory,
    const float* __restrict__ params, const float* __restrict__ Sv,
    const float* __restrict__ prev, float* __restrict__ out)
{
  __shared__ __align__(16) u16 pool[128*DMEM];
  __shared__ __align__(16) u16 meml[SPB*DMEM];
  __shared__ __align__(16) u16 halom[2*DMEM];
  __shared__ float invmn[SPB];
  __shared__ float invhn[2];
  __shared__ u16 hlo[128], hhi[128];
  const int t     = threadIdx.x;
  const int s0    = blockIdx.x * SPB;
  const int bbase = blockIdx.y * 128;
  {
    int r = t >> 3, c8 = t & 7;
    const float* mp = memory + (size_t)(s0 + r) * DMEM + c8 * 8;
    float4 f0 = *(const float4*)mp;
    float4 f1 = *(const float4*)(mp + 4);
    uint4 v;
    v.x = pk2(f0.x, f0.y); v.y = pk2(f0.z, f0.w);
    v.z = pk2(f1.x, f1.y); v.w = pk2(f1.z, f1.w);
    *(uint4*)&meml[r*DMEM + ((c8 ^ (r & 7)) << 3)] = v;
    float sq = f0.x*f0.x + f0.y*f0.y + f0.z*f0.z + f0.w*f0.w
             + f1.x*f1.x + f1.y*f1.y + f1.z*f1.z + f1.w*f1.w;
    sq += __shfl_xor(sq, 1, 64);
    sq += __shfl_xor(sq, 2, 64);
    sq += __shfl_xor(sq, 4, 64);
    if (c8 == 0) invmn[r] = rsqrtf(sq);
  }
  if (t < 128) {
    int h = t >> 6, m = t & 63;
    int gs = (s0 + (h ? SPB : -1)) & NMASK;
    float v = memory[(size_t)gs * DMEM + m];
    halom[h*DMEM + m] = f2bf(v);
    float sq = v * v;
#pragma unroll
    for (int d = 1; d < 64; d <<= 1) sq += __shfl_xor(sq, d, 64);
    if (m == 0) invhn[h] = rsqrtf(sq);
  }
  __syncthreads();
  const int w = t >> 6, L = t & 63;
  const int li = L & 15, hi4 = L >> 4;
  const int bb = bbase + w*16 + li;
  const int pb = w*16 + li;
  const uint4* kb = (const uint4*)(keysbf + (size_t)bb * DMEM);
  f32x4 zero = {0.f, 0.f, 0.f, 0.f};
  f32x4 acc[4];
#pragma unroll
  for (int rt = 0; rt < 4; ++rt) acc[rt] = zero;
#pragma unroll
  for (int ks = 0; ks < 2; ++ks) {
    int cb = ks*4 + hi4;
    bf16x8 bfr = __builtin_bit_cast(bf16x8, kb[cb]);
#pragma unroll
    for (int rt = 0; rt < 4; ++rt) {
      int r = rt*16 + li;
      bf16x8 af = __builtin_bit_cast(bf16x8, *(const uint4*)&meml[r*DMEM + ((cb ^ (r&7)) << 3)]);
      acc[rt] = __builtin_amdgcn_mfma_f32_16x16x32_bf16(af, bfr, acc[rt], 0, 0, 0);
    }
  }
  if (t < 256) {
    int hb = t & 127, hh = t >> 7;
    int gb = bbase + hb;
    const uint4* kb2 = (const uint4*)(keysbf + (size_t)gb * DMEM);
    float dot = 0.f;
#pragma unroll
    for (int mb = 0; mb < 8; ++mb) {
      uint4 kv = kb2[mb];
      uint4 mv = *(const uint4*)&halom[hh*DMEM + mb*8];
      dot += blo(kv.x)*blo(mv.x) + bhi(kv.x)*bhi(mv.x);
      dot += blo(kv.y)*blo(mv.y) + bhi(kv.y)*bhi(mv.y);
      dot += blo(kv.z)*blo(mv.z) + bhi(kv.z)*bhi(mv.z);
      dot += blo(kv.w)*blo(mv.w) + bhi(kv.w)*bhi(mv.w);
    }
    float abk2 = params[gb*8+0], C2 = params[gb*8+1], gg2 = params[gb*8+2];
    float l = dot * abk2 * invhn[hh];
    u16 hv = f2bf(__expf(l - C2) * gg2 / Sv[gb]);
    if (hh) hhi[hb] = hv; else hlo[hb] = hv;
  }
  {
    float abk = params[bb*8+0], C = params[bb*8+1], gg = params[bb*8+2];
    float wfac = gg / Sv[bb];
#pragma unroll
    for (int rt = 0; rt < 4; ++rt) {
      int sbase = rt*16 + hi4*4;
      float wv[4];
#pragma unroll
      for (int r = 0; r < 4; ++r) {
        int sl = sbase + r;
        wv[r] = __expf(acc[rt][r] * abk * invmn[sl] - C) * wfac;
      }
      uint2 pkd;
      pkd.x = pk2(wv[0], wv[1]);
      pkd.y = pk2(wv[2], wv[3]);
      *(uint2*)&pool[pb*DMEM + (((sbase >> 2) ^ (pb & 15)) << 2)] = pkd;
    }
  }
  __syncthreads();
  {
    const int g2 = t & 15;
    const int tb = t >> 4;
    const int so = g2 * 4;
#pragma unroll
    for (int p = 0; p < 4; ++p) {
      int pb2 = p*32 + tb;
      int bb2 = bbase + pb2;
      float gg = params[bb2*8+2];
      float c0 = params[bb2*8+3], c1 = params[bb2*8+4], c2 = params[bb2*8+5];
      float og = 1.f - gg;
      const float* pv = prev + (size_t)bb2 * NSLOTS;
      float4 pr = *(const float4*)(pv + s0 + so);
      uint2 wu = *(const uint2*)&pool[pb2*DMEM + ((g2 ^ (pb2 & 15)) << 2)];
      float w0 = blo(wu.x), w1 = bhi(wu.x), w2 = blo(wu.y), w3 = bhi(wu.y);
      float lpr = __shfl_up(pr.w, 1, 64);
      float rpr = __shfl_down(pr.x, 1, 64);
      float lw  = __shfl_up(w3, 1, 64);
      float rw  = __shfl_down(w0, 1, 64);
      if (g2 == 0)  { lpr = pv[(s0 - 1) & NMASK];   lw = bf2f(hlo[pb2]); }
      if (g2 == 15) { rpr = pv[(s0 + SPB) & NMASK]; rw = bf2f(hhi[pb2]); }
      float fm1 = fmaf(og, lpr,  lw);
      float f0  = fmaf(og, pr.x, w0);
      float f1  = fmaf(og, pr.y, w1);
      float f2  = fmaf(og, pr.z, w2);
      float f3  = fmaf(og, pr.w, w3);
      float f4  = fmaf(og, rpr,  rw);
      float4 o;
      o.x = c0*fm1 + c1*f0 + c2*f1;
      o.y = c0*f0  + c1*f1 + c2*f2;
      o.z = c0*f1  + c1*f2 + c2*f3;
      o.w = c0*f2  + c1*f3 + c2*f4;
      *(float4*)(out + (size_t)bb2 * NSLOTS + s0 + so) = o;
    }
  }
}

extern "C" void kernel_launch(void* const* d_in, const int* in_sizes, int n_in,
                              void* d_out, int out_size, void* d_ws, size_t ws_size,
                              hipStream_t stream)
{
  (void)in_sizes; (void)n_in; (void)out_size;
  const float* inp    = (const float*)d_in[0];
  const float* memory = (const float*)d_in[1];
  const float* prev   = (const float*)d_in[2];
  const float* W      = (const float*)d_in[3];
  const float* bias   = (const float*)d_in[4];
  float* out = (float*)d_out;
  char*  ws  = (char*)d_ws;

  u16*   keysbf = (u16*)ws;                    // 32 KB
  float* params = (float*)(ws + 32768);        // 8 KB
  float* Sv     = (float*)(ws + 40960);        // 1 KB
  float* sumpart = (float*)(ws + 49152);       // 1 MB (new) / 2 MB (fb)
  u16*   ug      = (u16*)(ws + 49152 + 1048576); // 67 MB

  const size_t need_new = 49152 + 1048576 + (size_t)NBATCH * NSLOTS * 2u;
  const size_t need_fb  = 49152 + (size_t)NBATCH * NBLK * 4u;

  hipLaunchKernelGGL(ntm_prep, dim3(NBATCH), dim3(128), 0, stream, inp, W, bias, keysbf, params);

  if (ws_size >= need_new) {
    hipLaunchKernelGGL(ntm_dots,   dim3(NSLOTS/256, NBATCH/64), dim3(512), 0, stream,
                       keysbf, memory, params, ug, sumpart);
    hipLaunchKernelGGL(ntm_reduce, dim3(NBATCH), dim3(256), 0, stream, sumpart, Sv, 1024);
    hipLaunchKernelGGL(ntm_conv,   dim3(NSLOTS/8192, NBATCH), dim3(256), 0, stream,
                       ug, params, Sv, prev, out);
  } else {
    float* sp = (ws_size >= need_fb) ? sumpart : out;
    hipLaunchKernelGGL(ntm_stats_fb, dim3(NBLK, 2), dim3(512), 0, stream, keysbf, memory, params, sp);
    hipLaunchKernelGGL(ntm_reduce,   dim3(NBATCH),  dim3(256), 0, stream, sp, Sv, NBLK);
    hipLaunchKernelGGL(ntm_final_fb, dim3(NBLK, 2), dim3(512), 0, stream, keysbf, memory, params, Sv, prev, out);
  }
}

// Round 6
// 126.963 us; speedup vs baseline: 1.3096x; 1.2930x over previous
//
#include <hip/hip_runtime.h>

#define NSLOTS 131072
#define NMASK  (NSLOTS-1)
#define NBATCH 256
#define DMEM   64
#define DIN    256
#define DCOMB  71
#define SPB    64                 // slots per fallback-stats tile
#define NBLK   (NSLOTS/SPB)       // 2048
#define EPSF   1e-8f

typedef unsigned int   u32;
typedef unsigned short u16;
typedef __bf16 bf16x8 __attribute__((ext_vector_type(8)));
typedef float  f32x4  __attribute__((ext_vector_type(4)));

__device__ __forceinline__ u16 f2bf(float f) {
  u32 u = __builtin_bit_cast(u32, f);
  u += 0x7fffu + ((u >> 16) & 1u);          // RNE
  return (u16)(u >> 16);
}
__device__ __forceinline__ float bf2f(u16 v) {
  return __builtin_bit_cast(float, ((u32)v) << 16);
}
__device__ __forceinline__ u32 pk2(float a, float b) {
  return (u32)f2bf(a) | ((u32)f2bf(b) << 16);
}
__device__ __forceinline__ float blo(u32 u){ return __builtin_bit_cast(float, u << 16); }
__device__ __forceinline__ float bhi(u32 u){ return __builtin_bit_cast(float, u & 0xffff0000u); }

// ---------------- kernel 1: combined GEMM + per-batch params ----------------
// params[b*8]: {abk = ks/kn, C = |ks|, gate, ck0, ck1, ck2, -, -}
__global__ __launch_bounds__(128) void ntm_prep(
    const float* __restrict__ inp, const float* __restrict__ W,
    const float* __restrict__ bias, u16* __restrict__ keysbf,
    float* __restrict__ params)
{
  __shared__ float comb[DCOMB];
  const int b = blockIdx.x;
  const int t = threadIdx.x;
  if (t < DCOMB) {
    float acc = bias[t];
    const float* ip = inp + (size_t)b * DIN;
    for (int i = 0; i < DIN; ++i) acc = fmaf(ip[i], W[i*DCOMB + t], acc);
    comb[t] = acc;
  }
  __syncthreads();
  if (t < 64) {
    float k = comb[t];
    keysbf[b*64 + t] = f2bf(k);
    float sq = k * k;
#pragma unroll
    for (int d = 1; d < 64; d <<= 1) sq += __shfl_xor(sq, d, 64);
    if (t == 0) {
      float kn = sqrtf(sq);
      float ks = comb[64];
      params[b*8+0] = ks / kn;                         // abk
      params[b*8+1] = fabsf(ks);                       // softmax shift C (>= max logit)
      params[b*8+2] = 1.f/(1.f + __expf(-comb[65]));   // gate
      float c0 = comb[66], c1 = comb[67], c2 = comb[68];
      float mx = fmaxf(c0, fmaxf(c1, c2));
      float e0 = __expf(c0-mx), e1 = __expf(c1-mx), e2 = __expf(c2-mx);
      float inv = 1.f/(e0+e1+e2);
      params[b*8+3] = e0*inv; params[b*8+4] = e1*inv; params[b*8+5] = e2*inv;
    }
  }
}

// ---------------- kernel A: dots -> u = exp(l - C) (bf16, coalesced) + partial sums ----------------
// tile: 256 slots x 64 batches. grid (512, 4).
__global__ __launch_bounds__(512, 6) void ntm_dots(
    const u16* __restrict__ keysbf, const float* __restrict__ memory,
    const float* __restrict__ params, u16* __restrict__ ug,
    float* __restrict__ sumpart)
{
  __shared__ __align__(16) u16 pool[64*256];        // 32 KB: u bf16, swizzled 8B chunks
  __shared__ __align__(16) u16 meml[64*DMEM];       // 8 KB subtile, swizzled
  __shared__ float invmn[64];
  const int t     = threadIdx.x;
  const int s0    = blockIdx.x * 256;
  const int bbase = blockIdx.y * 64;

  const int w   = t >> 6, L = t & 63;
  const int li  = L & 15, hi4 = L >> 4;
  const int bt  = w & 3;            // batch tile (16 batches)
  const int sh  = w >> 2;           // slot half of subtile (32 slots)
  const int bb  = bbase + bt*16 + li;
  const int prow = bt*16 + li;      // pool row 0..63
  const uint4* kb = (const uint4*)(keysbf + (size_t)bb * DMEM);
  const float abk = params[bb*8+0];
  const float C   = params[bb*8+1];
  float s_acc = 0.f;

  for (int st = 0; st < 4; ++st) {
    { // stage memory subtile (64 slots)
      int r = t >> 3, c8 = t & 7;
      const float* mp = memory + (size_t)(s0 + st*64 + r) * DMEM + c8 * 8;
      float4 f0 = *(const float4*)mp;
      float4 f1 = *(const float4*)(mp + 4);
      uint4 v;
      v.x = pk2(f0.x, f0.y); v.y = pk2(f0.z, f0.w);
      v.z = pk2(f1.x, f1.y); v.w = pk2(f1.z, f1.w);
      *(uint4*)&meml[r*DMEM + ((c8 ^ (r & 7)) << 3)] = v;
      float sq = f0.x*f0.x + f0.y*f0.y + f0.z*f0.z + f0.w*f0.w
               + f1.x*f1.x + f1.y*f1.y + f1.z*f1.z + f1.w*f1.w;
      sq += __shfl_xor(sq, 1, 64);
      sq += __shfl_xor(sq, 2, 64);
      sq += __shfl_xor(sq, 4, 64);
      if (c8 == 0) invmn[r] = rsqrtf(sq);
    }
    __syncthreads();

    f32x4 zero = {0.f, 0.f, 0.f, 0.f};
    f32x4 acc[2] = {zero, zero};
#pragma unroll
    for (int ks = 0; ks < 2; ++ks) {
      int cb = ks*4 + hi4;
      bf16x8 bfr = __builtin_bit_cast(bf16x8, kb[cb]);
#pragma unroll
      for (int rt = 0; rt < 2; ++rt) {
        int r = sh*32 + rt*16 + li;
        bf16x8 af = __builtin_bit_cast(bf16x8, *(const uint4*)&meml[r*DMEM + ((cb ^ (r&7)) << 3)]);
        acc[rt] = __builtin_amdgcn_mfma_f32_16x16x32_bf16(af, bfr, acc[rt], 0, 0, 0);
      }
    }

    // u -> pool (swizzled 8B chunks within this subtile's 16-chunk group)
#pragma unroll
    for (int rt = 0; rt < 2; ++rt) {
      int sbase = sh*32 + rt*16 + hi4*4;   // slot within subtile
      float wv[4];
#pragma unroll
      for (int r = 0; r < 4; ++r)
        wv[r] = __expf(acc[rt][r] * abk * invmn[sbase + r] - C);
      s_acc += wv[0] + wv[1] + wv[2] + wv[3];
      uint2 pkd;
      pkd.x = pk2(wv[0], wv[1]);
      pkd.y = pk2(wv[2], wv[3]);
      int chunk = st*16 + ((sbase >> 2) ^ (prow & 15));
      *(uint2*)&pool[prow*256 + chunk*4] = pkd;
    }
    __syncthreads();
  }

  // partial sums: reduce over hi4 groups (this wave covers 128 slots for batch bb)
  s_acc += __shfl_xor(s_acc, 16, 64);
  s_acc += __shfl_xor(s_acc, 32, 64);
  if (hi4 == 0) sumpart[(size_t)bb*1024 + blockIdx.x*2 + sh] = s_acc;

  // write u coalesced: 8 threads/row, 64 B each (512 B contiguous per row)
  {
    int row = t >> 3, seg = t & 7;
    uint2 wu[8];
#pragma unroll
    for (int j = 0; j < 8; ++j) {
      int c = seg*8 + j;
      int cs = (c & 48) | ((c ^ row) & 15);
      wu[j] = *(const uint2*)&pool[row*256 + cs*4];
    }
    uint4* dst = (uint4*)(ug + (size_t)(bbase + row) * NSLOTS + s0 + seg*32);
#pragma unroll
    for (int j2 = 0; j2 < 4; ++j2) {
      uint4 v; v.x = wu[j2*2].x; v.y = wu[j2*2].y; v.z = wu[j2*2+1].x; v.w = wu[j2*2+1].y;
      dst[j2] = v;
    }
  }
}

// ---------------- kernel 3: global S per batch ----------------
__global__ __launch_bounds__(256) void ntm_reduce(
    const float* __restrict__ sumpart, float* __restrict__ Sv, int nparts)
{
  __shared__ float red[4];
  const int b = blockIdx.x, t = threadIdx.x;
  const int w = t >> 6, L = t & 63;
  float s = 0.f;
  for (int i = t; i < nparts; i += 256) s += sumpart[(size_t)b*nparts + i];
#pragma unroll
  for (int d = 1; d < 64; d <<= 1) s += __shfl_xor(s, d, 64);
  if (L == 0) red[w] = s;
  __syncthreads();
  if (t == 0) Sv[b] = red[0] + red[1] + red[2] + red[3];
}

// ---------------- kernel B: pure streaming gate-blend + 3-tap circular conv (vectorized) ----------------
// grid (64, 256), 256 threads; block covers one batch row x 2048 slots; 8 slots/thread.
__global__ __launch_bounds__(256, 8) void ntm_conv(
    const u16* __restrict__ ug, const float* __restrict__ params,
    const float* __restrict__ Sv, const float* __restrict__ prev,
    float* __restrict__ out)
{
  const int b    = blockIdx.y;
  const int t    = threadIdx.x;
  const int so   = blockIdx.x * 2048 + t * 8;
  const int L    = t & 63;
  const float gg  = params[b*8+2];
  const float c0f = params[b*8+3], c1f = params[b*8+4], c2f = params[b*8+5];
  const float og  = 1.f - gg;
  const float gs  = gg / Sv[b];
  const float* pv = prev + (size_t)b * NSLOTS;
  const u16*   uv = ug   + (size_t)b * NSLOTS;
  float*       ov = out  + (size_t)b * NSLOTS;

  float4 p0 = *(const float4*)(pv + so);
  float4 p1 = *(const float4*)(pv + so + 4);
  uint4  uu = *(const uint4*)(uv + so);    // 8 bf16
  float f[8];
  f[0] = fmaf(og, p0.x, gs * blo(uu.x));
  f[1] = fmaf(og, p0.y, gs * bhi(uu.x));
  f[2] = fmaf(og, p0.z, gs * blo(uu.y));
  f[3] = fmaf(og, p0.w, gs * bhi(uu.y));
  f[4] = fmaf(og, p1.x, gs * blo(uu.z));
  f[5] = fmaf(og, p1.y, gs * bhi(uu.z));
  f[6] = fmaf(og, p1.z, gs * blo(uu.w));
  f[7] = fmaf(og, p1.w, gs * bhi(uu.w));

  float fl = __shfl_up(f[7], 1, 64);
  float fr = __shfl_down(f[0], 1, 64);
  if (L == 0) {                            // left edge of this wave's 512-slot span
    int sm = (so - 1) & NMASK;
    fl = fmaf(og, pv[sm], gs * bf2f(uv[sm]));
  }
  if (L == 63) {                           // right edge
    int sp = (so + 8) & NMASK;
    fr = fmaf(og, pv[sp], gs * bf2f(uv[sp]));
  }

  float4 o0, o1;
  o0.x = c0f*fl   + c1f*f[0] + c2f*f[1];
  o0.y = c0f*f[0] + c1f*f[1] + c2f*f[2];
  o0.z = c0f*f[1] + c1f*f[2] + c2f*f[3];
  o0.w = c0f*f[2] + c1f*f[3] + c2f*f[4];
  o1.x = c0f*f[3] + c1f*f[4] + c2f*f[5];
  o1.y = c0f*f[4] + c1f*f[5] + c2f*f[6];
  o1.z = c0f*f[5] + c1f*f[6] + c2f*f[7];
  o1.w = c0f*f[6] + c1f*f[7] + c2f*fr;
  *(float4*)(ov + so)     = o0;
  *(float4*)(ov + so + 4) = o1;
}

// ================= fallback path (ws too small): round-3 validated kernels =================
__global__ __launch_bounds__(512, 8) void ntm_stats_fb(
    const u16* __restrict__ keysbf, const float* __restrict__ memory,
    const float* __restrict__ params, float* __restrict__ sumpart)
{
  __shared__ __align__(16) u16 meml[SPB*DMEM];
  __shared__ float invmn[SPB];
  const int t     = threadIdx.x;
  const int s0    = blockIdx.x * SPB;
  const int bbase = blockIdx.y * 128;
  {
    int r = t >> 3, c8 = t & 7;
    const float* mp = memory + (size_t)(s0 + r) * DMEM + c8 * 8;
    float4 f0 = *(const float4*)mp;
    float4 f1 = *(const float4*)(mp + 4);
    uint4 v;
    v.x = pk2(f0.x, f0.y); v.y = pk2(f0.z, f0.w);
    v.z = pk2(f1.x, f1.y); v.w = pk2(f1.z, f1.w);
    *(uint4*)&meml[r*DMEM + ((c8 ^ (r & 7)) << 3)] = v;
    float sq = f0.x*f0.x + f0.y*f0.y + f0.z*f0.z + f0.w*f0.w
             + f1.x*f1.x + f1.y*f1.y + f1.z*f1.z + f1.w*f1.w;
    sq += __shfl_xor(sq, 1, 64);
    sq += __shfl_xor(sq, 2, 64);
    sq += __shfl_xor(sq, 4, 64);
    if (c8 == 0) invmn[r] = rsqrtf(sq);
  }
  __syncthreads();
  const int w = t >> 6, L = t & 63;
  const int li = L & 15, hi4 = L >> 4;
  const int bb = bbase + w*16 + li;
  const uint4* kb = (const uint4*)(keysbf + (size_t)bb * DMEM);
  f32x4 zero = {0.f, 0.f, 0.f, 0.f};
  f32x4 acc[4];
#pragma unroll
  for (int rt = 0; rt < 4; ++rt) acc[rt] = zero;
#pragma unroll
  for (int ks = 0; ks < 2; ++ks) {
    int cb = ks*4 + hi4;
    bf16x8 bfr = __builtin_bit_cast(bf16x8, kb[cb]);
#pragma unroll
    for (int rt = 0; rt < 4; ++rt) {
      int r = rt*16 + li;
      bf16x8 af = __builtin_bit_cast(bf16x8, *(const uint4*)&meml[r*DMEM + ((cb ^ (r&7)) << 3)]);
      acc[rt] = __builtin_amdgcn_mfma_f32_16x16x32_bf16(af, bfr, acc[rt], 0, 0, 0);
    }
  }
  float abk = params[bb*8 + 0];
  float C   = params[bb*8 + 1];
  float s = 0.f;
#pragma unroll
  for (int rt = 0; rt < 4; ++rt)
#pragma unroll
    for (int r = 0; r < 4; ++r) {
      int sl = rt*16 + hi4*4 + r;
      s += __expf(acc[rt][r] * abk * invmn[sl] - C);
    }
  s += __shfl_xor(s, 16, 64);
  s += __shfl_xor(s, 32, 64);
  if (hi4 == 0) sumpart[(size_t)bb*NBLK + blockIdx.x] = s;
}

__global__ __launch_bounds__(512, 8) void ntm_final_fb(
    const u16* __restrict__ keysbf, const float* __restrict__ memory,
    const float* __restrict__ params, const float* __restrict__ Sv,
    const float* __restrict__ prev, float* __restrict__ out)
{
  __shared__ __align__(16) u16 pool[128*DMEM];
  __shared__ __align__(16) u16 meml[SPB*DMEM];
  __shared__ __align__(16) u16 halom[2*DMEM];
  __shared__ float invmn[SPB];
  __shared__ float invhn[2];
  __shared__ u16 hlo[128], hhi[128];
  const int t     = threadIdx.x;
  const int s0    = blockIdx.x * SPB;
  const int bbase = blockIdx.y * 128;
  {
    int r = t >> 3, c8 = t & 7;
    const float* mp = memory + (size_t)(s0 + r) * DMEM + c8 * 8;
    float4 f0 = *(const float4*)mp;
    float4 f1 = *(const float4*)(mp + 4);
    uint4 v;
    v.x = pk2(f0.x, f0.y); v.y = pk2(f0.z, f0.w);
    v.z = pk2(f1.x, f1.y); v.w = pk2(f1.z, f1.w);
    *(uint4*)&meml[r*DMEM + ((c8 ^ (r & 7)) << 3)] = v;
    float sq = f0.x*f0.x + f0.y*f0.y + f0.z*f0.z + f0.w*f0.w
             + f1.x*f1.x + f1.y*f1.y + f1.z*f1.z + f1.w*f1.w;
    sq += __shfl_xor(sq, 1, 64);
    sq += __shfl_xor(sq, 2, 64);
    sq += __shfl_xor(sq, 4, 64);
    if (c8 == 0) invmn[r] = rsqrtf(sq);
  }
  if (t < 128) {
    int h = t >> 6, m = t & 63;
    int gs = (s0 + (h ? SPB : -1)) & NMASK;
    float v = memory[(size_t)gs * DMEM + m];
    halom[h*DMEM + m] = f2bf(v);
    float sq = v * v;
#pragma unroll
    for (int d = 1; d < 64; d <<= 1) sq += __shfl_xor(sq, d, 64);
    if (m == 0) invhn[h] = rsqrtf(sq);
  }
  __syncthreads();
  const int w = t >> 6, L = t & 63;
  const int li = L & 15, hi4 = L >> 4;
  const int bb = bbase + w*16 + li;
  const int pb = w*16 + li;
  const uint4* kb = (const uint4*)(keysbf + (size_t)bb * DMEM);
  f32x4 zero = {0.f, 0.f, 0.f, 0.f};
  f32x4 acc[4];
#pragma unroll
  for (int rt = 0; rt < 4; ++rt) acc[rt] = zero;
#pragma unroll
  for (int ks = 0; ks < 2; ++ks) {
    int cb = ks*4 + hi4;
    bf16x8 bfr = __builtin_bit_cast(bf16x8, kb[cb]);
#pragma unroll
    for (int rt = 0; rt < 4; ++rt) {
      int r = rt*16 + li;
      bf16x8 af = __builtin_bit_cast(bf16x8, *(const uint4*)&meml[r*DMEM + ((cb ^ (r&7)) << 3)]);
      acc[rt] = __builtin_amdgcn_mfma_f32_16x16x32_bf16(af, bfr, acc[rt], 0, 0, 0);
    }
  }
  if (t < 256) {
    int hb = t & 127, hh = t >> 7;
    int gb = bbase + hb;
    const uint4* kb2 = (const uint4*)(keysbf + (size_t)gb * DMEM);
    float dot = 0.f;
#pragma unroll
    for (int mb = 0; mb < 8; ++mb) {
      uint4 kv = kb2[mb];
      uint4 mv = *(const uint4*)&halom[hh*DMEM + mb*8];
      dot += blo(kv.x)*blo(mv.x) + bhi(kv.x)*bhi(mv.x);
      dot += blo(kv.y)*blo(mv.y) + bhi(kv.y)*bhi(mv.y);
      dot += blo(kv.z)*blo(mv.z) + bhi(kv.z)*bhi(mv.z);
      dot += blo(kv.w)*blo(mv.w) + bhi(kv.w)*bhi(mv.w);
    }
    float abk2 = params[gb*8+0], C2 = params[gb*8+1], gg2 = params[gb*8+2];
    float l = dot * abk2 * invhn[hh];
    u16 hv = f2bf(__expf(l - C2) * gg2 / Sv[gb]);
    if (hh) hhi[hb] = hv; else hlo[hb] = hv;
  }
  {
    float abk = params[bb*8+0], C = params[bb*8+1], gg = params[bb*8+2];
    float wfac = gg / Sv[bb];
#pragma unroll
    for (int rt = 0; rt < 4; ++rt) {
      int sbase = rt*16 + hi4*4;
      float wv[4];
#pragma unroll
      for (int r = 0; r < 4; ++r) {
        int sl = sbase + r;
        wv[r] = __expf(acc[rt][r] * abk * invmn[sl] - C) * wfac;
      }
      uint2 pkd;
      pkd.x = pk2(wv[0], wv[1]);
      pkd.y = pk2(wv[2], wv[3]);
      *(uint2*)&pool[pb*DMEM + (((sbase >> 2) ^ (pb & 15)) << 2)] = pkd;
    }
  }
  __syncthreads();
  {
    const int g2 = t & 15;
    const int tb = t >> 4;
    const int so = g2 * 4;
#pragma unroll
    for (int p = 0; p < 4; ++p) {
      int pb2 = p*32 + tb;
      int bb2 = bbase + pb2;
      float gg = params[bb2*8+2];
      float c0 = params[bb2*8+3], c1 = params[bb2*8+4], c2 = params[bb2*8+5];
      float og = 1.f - gg;
      const float* pv = prev + (size_t)bb2 * NSLOTS;
      float4 pr = *(const float4*)(pv + s0 + so);
      uint2 wu = *(const uint2*)&pool[pb2*DMEM + ((g2 ^ (pb2 & 15)) << 2)];
      float w0 = blo(wu.x), w1 = bhi(wu.x), w2 = blo(wu.y), w3 = bhi(wu.y);
      float lpr = __shfl_up(pr.w, 1, 64);
      float rpr = __shfl_down(pr.x, 1, 64);
      float lw  = __shfl_up(w3, 1, 64);
      float rw  = __shfl_down(w0, 1, 64);
      if (g2 == 0)  { lpr = pv[(s0 - 1) & NMASK];   lw = bf2f(hlo[pb2]); }
      if (g2 == 15) { rpr = pv[(s0 + SPB) & NMASK]; rw = bf2f(hhi[pb2]); }
      float fm1 = fmaf(og, lpr,  lw);
      float f0  = fmaf(og, pr.x, w0);
      float f1  = fmaf(og, pr.y, w1);
      float f2  = fmaf(og, pr.z, w2);
      float f3  = fmaf(og, pr.w, w3);
      float f4  = fmaf(og, rpr,  rw);
      float4 o;
      o.x = c0*fm1 + c1*f0 + c2*f1;
      o.y = c0*f0  + c1*f1 + c2*f2;
      o.z = c0*f1  + c1*f2 + c2*f3;
      o.w = c0*f2  + c1*f3 + c2*f4;
      *(float4*)(out + (size_t)bb2 * NSLOTS + s0 + so) = o;
    }
  }
}

extern "C" void kernel_launch(void* const* d_in, const int* in_sizes, int n_in,
                              void* d_out, int out_size, void* d_ws, size_t ws_size,
                              hipStream_t stream)
{
  (void)in_sizes; (void)n_in; (void)out_size;
  const float* inp    = (const float*)d_in[0];
  const float* memory = (const float*)d_in[1];
  const float* prev   = (const float*)d_in[2];
  const float* W      = (const float*)d_in[3];
  const float* bias   = (const float*)d_in[4];
  float* out = (float*)d_out;
  char*  ws  = (char*)d_ws;

  u16*   keysbf = (u16*)ws;                    // 32 KB
  float* params = (float*)(ws + 32768);        // 8 KB
  float* Sv     = (float*)(ws + 40960);        // 1 KB
  float* sumpart = (float*)(ws + 49152);       // 1 MB (new) / 2 MB (fb)
  u16*   ug      = (u16*)(ws + 49152 + 1048576); // 67 MB

  const size_t need_new = 49152 + 1048576 + (size_t)NBATCH * NSLOTS * 2u;
  const size_t need_fb  = 49152 + (size_t)NBATCH * NBLK * 4u;

  hipLaunchKernelGGL(ntm_prep, dim3(NBATCH), dim3(128), 0, stream, inp, W, bias, keysbf, params);

  if (ws_size >= need_new) {
    hipLaunchKernelGGL(ntm_dots,   dim3(NSLOTS/256, NBATCH/64), dim3(512), 0, stream,
                       keysbf, memory, params, ug, sumpart);
    hipLaunchKernelGGL(ntm_reduce, dim3(NBATCH), dim3(256), 0, stream, sumpart, Sv, 1024);
    hipLaunchKernelGGL(ntm_conv,   dim3(NSLOTS/2048, NBATCH), dim3(256), 0, stream,
                       ug, params, Sv, prev, out);
  } else {
    float* sp = (ws_size >= need_fb) ? sumpart : out;
    hipLaunchKernelGGL(ntm_stats_fb, dim3(NBLK, 2), dim3(512), 0, stream, keysbf, memory, params, sp);
    hipLaunchKernelGGL(ntm_reduce,   dim3(NBATCH),  dim3(256), 0, stream, sp, Sv, NBLK);
    hipLaunchKernelGGL(ntm_final_fb, dim3(NBLK, 2), dim3(512), 0, stream, keysbf, memory, params, Sv, prev, out);
  }
}